// Round 8
// baseline (217.009 us; speedup 1.0000x reference)
//
#include <hip/hip_runtime.h>

#define NB_ 32
#define NP_ 65536
#define NT_ 16
#define HB 1024
#define HSCALE 128.0f
#define NBX 64     // kernel1 blocks per batch (1024 priors each)

__device__ __forceinline__ float softplus_(float x) {
    // log(1 + e^x), stable
    return fmaxf(x, 0.0f) + __logf(1.0f + __expf(-fabsf(x)));
}

__device__ __forceinline__ float iou_fast(float tx0, float ty0, float tx1, float ty1, float ta,
                                          float bx0, float by0, float bx1, float by1, float ar) {
    float lx = fmaxf(tx0, bx0), ly = fmaxf(ty0, by0);
    float rx = fminf(tx1, bx1), ry = fminf(ty1, by1);
    float w = fmaxf(rx - lx, 0.0f), h = fmaxf(ry - ly, 0.0f);
    float inter = w * h;
    return __fdividef(inter, ta + ar - inter);
}

// ---- DPP wave64 reductions (result valid in lane 63) ----
#define DPP_STEP(x, t, ctrl, rmask, bmask, OP)                                          \
    t = __builtin_amdgcn_update_dpp(0, (x), (ctrl), (rmask), (bmask), true); OP;

__device__ __forceinline__ unsigned wave_max_u32(unsigned v) {
    int x = (int)v, t;
    DPP_STEP(x, t, 0x111, 0xf, 0xf, x = ((unsigned)t > (unsigned)x) ? t : x)
    DPP_STEP(x, t, 0x112, 0xf, 0xf, x = ((unsigned)t > (unsigned)x) ? t : x)
    DPP_STEP(x, t, 0x114, 0xf, 0xe, x = ((unsigned)t > (unsigned)x) ? t : x)
    DPP_STEP(x, t, 0x118, 0xf, 0xc, x = ((unsigned)t > (unsigned)x) ? t : x)
    DPP_STEP(x, t, 0x142, 0xa, 0xf, x = ((unsigned)t > (unsigned)x) ? t : x)
    DPP_STEP(x, t, 0x143, 0xc, 0xf, x = ((unsigned)t > (unsigned)x) ? t : x)
    return (unsigned)x;
}

__device__ __forceinline__ float wave_sum_f32(float v) {
    int x = __float_as_int(v), t;
    float f;
    DPP_STEP(x, t, 0x111, 0xf, 0xf, f = __int_as_float(x) + __int_as_float(t); x = __float_as_int(f))
    DPP_STEP(x, t, 0x112, 0xf, 0xf, f = __int_as_float(x) + __int_as_float(t); x = __float_as_int(f))
    DPP_STEP(x, t, 0x114, 0xf, 0xe, f = __int_as_float(x) + __int_as_float(t); x = __float_as_int(f))
    DPP_STEP(x, t, 0x118, 0xf, 0xc, f = __int_as_float(x) + __int_as_float(t); x = __float_as_int(f))
    DPP_STEP(x, t, 0x142, 0xa, 0xf, f = __int_as_float(x) + __int_as_float(t); x = __float_as_int(f))
    DPP_STEP(x, t, 0x143, 0xc, 0xf, f = __int_as_float(x) + __int_as_float(t); x = __float_as_int(f))
    return __int_as_float(x);
}

__device__ __forceinline__ int wave_sum_i32(int v) {
    int x = v, t;
    DPP_STEP(x, t, 0x111, 0xf, 0xf, x = x + t)
    DPP_STEP(x, t, 0x112, 0xf, 0xf, x = x + t)
    DPP_STEP(x, t, 0x114, 0xf, 0xe, x = x + t)
    DPP_STEP(x, t, 0x118, 0xf, 0xc, x = x + t)
    DPP_STEP(x, t, 0x142, 0xa, 0xf, x = x + t)
    DPP_STEP(x, t, 0x143, 0xc, 0xf, x = x + t)
    return x;
}

// Kernel 1: fused match + losses. R13: NO histogram here — stores raw
// per-prior loss_c_mine (f32, coalesced) instead; finishK bins it. Removes
// hist init + 8 LDS atomics/thread + LDS re-read + mixed-width writeback,
// and cuts hist global traffic 25 MB -> 16.8 MB.
// History: R3 fusion (2048 fences) 6x regression; R4 96-fence split null;
// R12 unconditional prefetch null (FETCH +7.4MB, VGPR 88 -> lost a wave slot).
// Keep kernels fence-free; in-branch loads are fine.
__global__ void __launch_bounds__(256) mainK(
    const float* __restrict__ loc, const float* __restrict__ conf,
    const float* __restrict__ priors, const float* __restrict__ targets,
    float* __restrict__ lcm,
    unsigned long long* __restrict__ bestPart,
    float* __restrict__ part_ll, float* __restrict__ part_pc, int* __restrict__ part_np)
{
    const int bx = blockIdx.x, b = blockIdx.y, tid = threadIdx.x;

    __shared__ float4 trb[NT_];   // x0,y0,x1,y1
    __shared__ float tra[NT_];    // area
    __shared__ unsigned wkey[4][NT_], wp[4][NT_];
    __shared__ float sh_ll[4], sh_pc[4];
    __shared__ int sh_np[4];

    if (tid < NT_) {
        const float* tp = targets + ((size_t)b * NT_ + tid) * 5;
        float x0 = tp[0], y0 = tp[1], x1 = tp[2], y1 = tp[3];
        trb[tid] = make_float4(x0, y0, x1, y1);
        tra[tid] = (x1 - x0) * (y1 - y0);
    }
    __syncthreads();

    const int pbase = bx * 1024 + tid;
    float pbx0[4], pby0[4], pbx1[4], pby1[4], par[4];
    float2 cxy[4];
#pragma unroll
    for (int i = 0; i < 4; i++) {
        float4 pr = ((const float4*)priors)[pbase + 256 * i];
        cxy[i] = ((const float2*)conf)[(size_t)b * NP_ + pbase + 256 * i];  // in flight during t-loop
        float hw = pr.z * 0.5f, hh = pr.w * 0.5f;
        pbx0[i] = pr.x - hw; pby0[i] = pr.y - hh;
        pbx1[i] = pr.x + hw; pby1[i] = pr.y + hh;
        par[i] = (pbx1[i] - pbx0[i]) * (pby1[i] - pby0[i]);
    }

    unsigned pkey[4] = {0u, 0u, 0u, 0u};  // per-prior best (iou_key | (15-t))
    unsigned tkey[NT_];                   // per-truth best (iou_key | (15-i))
#pragma unroll
    for (int t = 0; t < NT_; t++) tkey[t] = 0u;

#pragma unroll
    for (int t = 0; t < NT_; t++) {
        float4 tb = trb[t];          // ds_read_b128 (broadcast)
        float ta = tra[t];           // ds_read_b32
#pragma unroll
        for (int i = 0; i < 4; i++) {
            float iou = iou_fast(tb.x, tb.y, tb.z, tb.w, ta,
                                 pbx0[i], pby0[i], pbx1[i], pby1[i], par[i]);
            // monotone u32 key; 2 LSB mantissa bits -> 4-bit tie-break index
            // (ties prefer smaller t / smaller prior index)
            unsigned base = (__float_as_uint(iou) & 0xFFFFFFFCu) << 2;
            unsigned kt = base | (unsigned)(15 - t);
            unsigned kp = base | (unsigned)(15 - i);
            pkey[i] = (kt > pkey[i]) ? kt : pkey[i];
            tkey[t] = (kp > tkey[t]) ? kp : tkey[t];
        }
    }

    float ll_acc = 0.0f, pc_acc = 0.0f;
    int np_acc = 0;
#pragma unroll
    for (int i = 0; i < 4; i++) {
        int p = pbase + 256 * i;
        size_t bp = (size_t)b * NP_ + p;
        bool pos = (pkey[i] >= 0xFC000000u);  // iou >= 0.5 (0.5 has zero low bits)
        float dd = cxy[i].y - cxy[i].x;
        float v = pos ? 0.0f : softplus_(dd);  // loss_c_mine
        lcm[bp] = v;                           // raw value out; finishK bins it
        if (pos) {
            np_acc++;
            pc_acc += softplus_(-dd);  // lse - c.y
            int t = 15 - (int)(pkey[i] & 15u);
            float4 tb = trb[t];
            float4 prv = ((const float4*)priors)[p];  // reload: same bits as staging load
            float gcx = ((tb.x + tb.z) * 0.5f - prv.x) / (0.1f * prv.z);
            float gcy = ((tb.y + tb.w) * 0.5f - prv.y) / (0.1f * prv.w);
            float gw = __logf((tb.z - tb.x) / prv.z) * 5.0f;
            float gh = __logf((tb.w - tb.y) / prv.w) * 5.0f;
            float4 ld = ((const float4*)loc)[bp];
            float d0 = fabsf(ld.x - gcx), d1 = fabsf(ld.y - gcy);
            float d2 = fabsf(ld.z - gw),  d3 = fabsf(ld.w - gh);
            ll_acc += (d0 < 1.0f) ? 0.5f * d0 * d0 : d0 - 0.5f;
            ll_acc += (d1 < 1.0f) ? 0.5f * d1 * d1 : d1 - 0.5f;
            ll_acc += (d2 < 1.0f) ? 0.5f * d2 * d2 : d2 - 0.5f;
            ll_acc += (d3 < 1.0f) ? 0.5f * d3 * d3 : d3 - 0.5f;
        }
    }

    // per-wave reductions — DPP chains (VALU), no LDS pipe
    const int wave = tid >> 6, lane = tid & 63;
#pragma unroll
    for (int t = 0; t < NT_; t++) {
        unsigned k = tkey[t];
        unsigned m = (unsigned)__builtin_amdgcn_readlane((int)wave_max_u32(k), 63);
        unsigned long long ball = __ballot(k == m);
        if (lane == 0) {
            int l = __ffsll((long long)ball) - 1;  // lowest lane = smallest p (same i)
            int ci = 15 - (int)(m & 15u);
            int p = bx * 1024 + ci * 256 + wave * 64 + l;
            wkey[wave][t] = m;
            wp[wave][t] = (unsigned)p;
        }
    }
    {
        float llw = wave_sum_f32(ll_acc);
        float pcw = wave_sum_f32(pc_acc);
        int npw = wave_sum_i32(np_acc);
        if (lane == 63) { sh_ll[wave] = llw; sh_pc[wave] = pcw; sh_np[wave] = npw; }
    }
    __syncthreads();

    if (tid < NT_) {
        unsigned bk = wkey[0][tid], bpv = wp[0][tid];
        for (int w = 1; w < 4; w++) {
            unsigned k2 = wkey[w][tid], p2 = wp[w][tid];
            if (k2 > bk || (k2 == bk && p2 < bpv)) { bk = k2; bpv = p2; }
        }
        unsigned long long pk = (((unsigned long long)bk) << 32) | (unsigned)(~bpv);
        bestPart[((size_t)b * NT_ + tid) * NBX + bx] = pk;   // plain store
    }
    if (tid == 0) {
        part_ll[b * NBX + bx] = sh_ll[0] + sh_ll[1] + sh_ll[2] + sh_ll[3];
        part_pc[b * NBX + bx] = sh_pc[0] + sh_pc[1] + sh_pc[2] + sh_pc[3];
        part_np[b * NBX + bx] = sh_np[0] + sh_np[1] + sh_np[2] + sh_np[3];
    }
}

// Kernel 2 (R13): one block per batch, fully independent (zero fences /
// tickets / global atomics — R3/R4 lesson). Builds the 1024-bin histogram
// directly from raw lcm values (64/thread, LDS atomics — same binning
// arithmetic on the same bits mainK used to bin), then identical fixup +
// selection as before. bestPart via 16 waves x 64-lane shuffle-max; part
// sums via DPP fixed tree.
__global__ void __launch_bounds__(1024) finishK(
    const float* __restrict__ loc, const float* __restrict__ conf,
    const float* __restrict__ priors, const float* __restrict__ targets,
    const float* __restrict__ lcm,
    const unsigned long long* __restrict__ bestPart,
    const float* __restrict__ part_ll, const float* __restrict__ part_pc,
    const int* __restrict__ part_np,
    float* __restrict__ final_l, float* __restrict__ final_c, int* __restrict__ final_n)
{
    const int b = blockIdx.x, tid = threadIdx.x;  // 1024 threads
    __shared__ int hc[HB];
    __shared__ float hs[HB];
    __shared__ float4 trb[NT_];
    __shared__ float tra[NT_];
    __shared__ unsigned ps[NT_];
    __shared__ float s_dll, s_dpc, s_sll, s_spc;
    __shared__ int s_dnp, s_sn;
    __shared__ unsigned ccnt[16];
    __shared__ float csm[16];

    if (tid == 0) { s_dll = 0.0f; s_dpc = 0.0f; s_dnp = 0; }
    if (tid < NT_) {
        const float* tp = targets + ((size_t)b * NT_ + tid) * 5;
        float x0 = tp[0], y0 = tp[1], x1 = tp[2], y1 = tp[3];
        trb[tid] = make_float4(x0, y0, x1, y1);
        tra[tid] = (x1 - x0) * (y1 - y0);
    }
    hc[tid] = 0; hs[tid] = 0.0f;   // HB == 1024
    __syncthreads();

    // hist build from raw values: 64 coalesced loads/thread + LDS atomics.
    // Binning arithmetic identical to the old mainK path (same f32 bits).
    {
        const float* lp = lcm + (size_t)b * NP_;
#pragma unroll 8
        for (int j = 0; j < 64; j++) {
            float v = lp[tid + 1024 * j];
            int bin = min(HB - 1, (int)(v * HSCALE));
            atomicAdd(&hc[bin], 1);
            atomicAdd(&hs[bin], v);
        }
    }

    // bestPart: one wave per truth, 64 lanes = 64 partials; u64 max is
    // order-free and keys are unique (low bits = ~p) -> deterministic
    {
        const int tr_i = tid >> 6, lane = tid & 63;
        unsigned long long v = bestPart[((size_t)b * NT_ + tr_i) * NBX + lane];
        for (int off = 32; off > 0; off >>= 1) {
            unsigned long long u = __shfl_down(v, off, 64);
            v = (u > v) ? u : v;
        }
        if (lane == 0) ps[tr_i] = ~((unsigned)(v & 0xffffffffULL));
    }
    // part sums: 64 lanes, fixed DPP tree (deterministic)
    if (tid < 64) {
        float lv = part_ll[b * NBX + tid];
        float pv = part_pc[b * NBX + tid];
        int nv = part_np[b * NBX + tid];
        lv = wave_sum_f32(lv); pv = wave_sum_f32(pv); nv = wave_sum_i32(nv);
        if (tid == 63) { s_sll = lv; s_spc = pv; s_sn = nv; }
    }
    __syncthreads();

    // fixup (16 threads) — adjustments into LDS; identical math to main pass
    if (tid < NT_) {
        unsigned p = ps[tid];
        bool active = true;
        for (int u = tid + 1; u < NT_; u++)
            if (ps[u] == p) { active = false; break; }  // last-wins dedup
        if (active) {
            float4 prv = ((const float4*)priors)[p];
            float hw = prv.z * 0.5f, hh = prv.w * 0.5f;
            float qx0 = prv.x - hw, qy0 = prv.y - hh;
            float qx1 = prv.x + hw, qy1 = prv.y + hh;
            float areab = (qx1 - qx0) * (qy1 - qy0);
            unsigned pk = 0u;
            for (int tt = 0; tt < NT_; tt++) {
                float4 tb = trb[tt];
                float iou = iou_fast(tb.x, tb.y, tb.z, tb.w, tra[tt],
                                     qx0, qy0, qx1, qy1, areab);
                unsigned cand = ((__float_as_uint(iou) & 0xFFFFFFFCu) << 2)
                              | (unsigned)(15 - tt);
                pk = (cand > pk) ? cand : pk;
            }
            bool pos0 = (pk >= 0xFC000000u);   // identical rule to kernel1
            int t0 = 15 - (int)(pk & 15u);
            size_t bp = (size_t)b * NP_ + p;
            float2 cxyf = ((const float2*)conf)[bp];
            float dd = cxyf.y - cxyf.x;
            float4 ld = ((const float4*)loc)[bp];

            auto sl1_of = [&](int tt) -> float {
                float4 tb = trb[tt];
                float gcx = ((tb.x + tb.z) * 0.5f - prv.x) / (0.1f * prv.z);
                float gcy = ((tb.y + tb.w) * 0.5f - prv.y) / (0.1f * prv.w);
                float gw = __logf((tb.z - tb.x) / prv.z) * 5.0f;
                float gh = __logf((tb.w - tb.y) / prv.w) * 5.0f;
                float d0 = fabsf(ld.x - gcx), d1 = fabsf(ld.y - gcy);
                float d2 = fabsf(ld.z - gw),  d3 = fabsf(ld.w - gh);
                float s = (d0 < 1.0f) ? 0.5f * d0 * d0 : d0 - 0.5f;
                s += (d1 < 1.0f) ? 0.5f * d1 * d1 : d1 - 0.5f;
                s += (d2 < 1.0f) ? 0.5f * d2 * d2 : d2 - 0.5f;
                s += (d3 < 1.0f) ? 0.5f * d3 * d3 : d3 - 0.5f;
                return s;
            };
            float dll = sl1_of(tid) - (pos0 ? sl1_of(t0) : 0.0f);
            atomicAdd(&s_dll, dll);            // LDS atomic, single wave -> fixed HW order
            if (!pos0) {
                float v = softplus_(dd);       // same expr/bits as mainK's stored value
                int bin = min(HB - 1, (int)(v * HSCALE));
                atomicSub(&hc[bin], 1);
                atomicAdd(&hs[bin], -v);
                atomicAdd(&s_dpc, softplus_(-dd));
                atomicAdd(&s_dnp, 1);
            }
        }
    }
    __syncthreads();

    if (tid < 16) {
        unsigned cacc = 0; float sacc = 0.0f;
        for (int j = 0; j < 64; j++) { cacc += (unsigned)hc[tid * 64 + j]; sacc += hs[tid * 64 + j]; }
        ccnt[tid] = cacc; csm[tid] = sacc;
    }
    __syncthreads();

    if (tid == 0) {
        float sll = s_sll + s_dll;
        float spc = s_spc + s_dpc;
        int n = s_sn + s_dnp;
        int K = 3 * n;
        if (K > NP_ - 1) K = NP_ - 1;
        float tk = 0.0f;
        if (K > 0) {
            unsigned need = (unsigned)K, cum = 0;
            float s = 0.0f;
            int cb = 15;
            for (; cb > 0; --cb) {
                if (cum + ccnt[cb] >= need) break;
                cum += ccnt[cb]; s += csm[cb];
            }
            int bin = cb * 64 + 63;
            for (; bin > cb * 64; --bin) {
                if (cum + (unsigned)hc[bin] >= need) break;
                cum += (unsigned)hc[bin]; s += hs[bin];
            }
            unsigned rem = need - cum;
            int cv = hc[bin];
            float avg = (cv > 0) ? __fdividef(hs[bin], (float)cv) : 0.0f;
            tk = s + (float)rem * avg;
        }
        final_l[b] = sll;
        final_c[b] = spc + tk;
        final_n[b] = n;
        // no fence: kernel boundary orders these stores before lastK
    }
}

// Kernel 3: trivial cross-batch reduce. Ordered by kernel boundary.
__global__ void __launch_bounds__(64) lastK(
    const float* __restrict__ final_l, const float* __restrict__ final_c,
    const int* __restrict__ final_n, float* __restrict__ out)
{
    const int tid = threadIdx.x;
    float lv = 0.0f, cv = 0.0f;
    int nv = 0;
    if (tid < NB_) { lv = final_l[tid]; cv = final_c[tid]; nv = final_n[tid]; }
    for (int off = 32; off > 0; off >>= 1) {
        lv += __shfl_down(lv, off, 64);
        cv += __shfl_down(cv, off, 64);
        nv += __shfl_down(nv, off, 64);
    }
    if (tid == 0) {
        float fn = (float)nv;
        out[0] = lv / fn;
        out[1] = cv / fn;
    }
}

extern "C" void kernel_launch(void* const* d_in, const int* in_sizes, int n_in,
                              void* d_out, int out_size, void* d_ws, size_t ws_size,
                              hipStream_t stream) {
    const float* loc = (const float*)d_in[0];
    const float* conf = (const float*)d_in[1];
    const float* priors = (const float*)d_in[2];
    const float* targets = (const float*)d_in[3];
    float* out = (float*)d_out;

    char* w = (char*)d_ws;
    float* lcm = (float*)w;                                // 32*65536*4 = 8 MB
    char* acc = w + (8u << 20);
    unsigned long long* bestPart = (unsigned long long*)acc;        // 256 KB
    float* part_ll = (float*)(acc + 262144);                        // 8 KB
    float* part_pc = (float*)(acc + 270336);                        // 8 KB
    int* part_np   = (int*)(acc + 278528);                          // 8 KB
    float* final_l = (float*)(acc + 286720);                        // 128 B
    float* final_c = (float*)(acc + 286848);                        // 128 B
    int* final_n   = (int*)(acc + 286976);                          // 128 B

    mainK<<<dim3(NBX, NB_), 256, 0, stream>>>(loc, conf, priors, targets,
                                              lcm, bestPart,
                                              part_ll, part_pc, part_np);
    finishK<<<NB_, 1024, 0, stream>>>(loc, conf, priors, targets,
                                      lcm, bestPart,
                                      part_ll, part_pc, part_np,
                                      final_l, final_c, final_n);
    lastK<<<1, 64, 0, stream>>>(final_l, final_c, final_n, out);
}

// Round 9
// 147.455 us; speedup vs baseline: 1.4717x; 1.4717x over previous
//
#include <hip/hip_runtime.h>

#define NB_ 32
#define NP_ 65536
#define NT_ 16
#define HB 1024
#define HSCALE 128.0f
#define NBX 32     // kernel1 blocks per batch (2048 priors each, 512 threads)

__device__ __forceinline__ float softplus_(float x) {
    // log(1 + e^x), stable
    return fmaxf(x, 0.0f) + __logf(1.0f + __expf(-fabsf(x)));
}

__device__ __forceinline__ float iou_fast(float tx0, float ty0, float tx1, float ty1, float ta,
                                          float bx0, float by0, float bx1, float by1, float ar) {
    float lx = fmaxf(tx0, bx0), ly = fmaxf(ty0, by0);
    float rx = fminf(tx1, bx1), ry = fminf(ty1, by1);
    float w = fmaxf(rx - lx, 0.0f), h = fmaxf(ry - ly, 0.0f);
    float inter = w * h;
    return __fdividef(inter, ta + ar - inter);
}

// ---- DPP wave64 reductions (result valid in lane 63) ----
#define DPP_STEP(x, t, ctrl, rmask, bmask, OP)                                          \
    t = __builtin_amdgcn_update_dpp(0, (x), (ctrl), (rmask), (bmask), true); OP;

__device__ __forceinline__ unsigned wave_max_u32(unsigned v) {
    int x = (int)v, t;
    DPP_STEP(x, t, 0x111, 0xf, 0xf, x = ((unsigned)t > (unsigned)x) ? t : x)
    DPP_STEP(x, t, 0x112, 0xf, 0xf, x = ((unsigned)t > (unsigned)x) ? t : x)
    DPP_STEP(x, t, 0x114, 0xf, 0xe, x = ((unsigned)t > (unsigned)x) ? t : x)
    DPP_STEP(x, t, 0x118, 0xf, 0xc, x = ((unsigned)t > (unsigned)x) ? t : x)
    DPP_STEP(x, t, 0x142, 0xa, 0xf, x = ((unsigned)t > (unsigned)x) ? t : x)
    DPP_STEP(x, t, 0x143, 0xc, 0xf, x = ((unsigned)t > (unsigned)x) ? t : x)
    return (unsigned)x;
}

__device__ __forceinline__ float wave_sum_f32(float v) {
    int x = __float_as_int(v), t;
    float f;
    DPP_STEP(x, t, 0x111, 0xf, 0xf, f = __int_as_float(x) + __int_as_float(t); x = __float_as_int(f))
    DPP_STEP(x, t, 0x112, 0xf, 0xf, f = __int_as_float(x) + __int_as_float(t); x = __float_as_int(f))
    DPP_STEP(x, t, 0x114, 0xf, 0xe, f = __int_as_float(x) + __int_as_float(t); x = __float_as_int(f))
    DPP_STEP(x, t, 0x118, 0xf, 0xc, f = __int_as_float(x) + __int_as_float(t); x = __float_as_int(f))
    DPP_STEP(x, t, 0x142, 0xa, 0xf, f = __int_as_float(x) + __int_as_float(t); x = __float_as_int(f))
    DPP_STEP(x, t, 0x143, 0xc, 0xf, f = __int_as_float(x) + __int_as_float(t); x = __float_as_int(f))
    return __int_as_float(x);
}

__device__ __forceinline__ int wave_sum_i32(int v) {
    int x = v, t;
    DPP_STEP(x, t, 0x111, 0xf, 0xf, x = x + t)
    DPP_STEP(x, t, 0x112, 0xf, 0xf, x = x + t)
    DPP_STEP(x, t, 0x114, 0xf, 0xe, x = x + t)
    DPP_STEP(x, t, 0x118, 0xf, 0xc, x = x + t)
    DPP_STEP(x, t, 0x142, 0xa, 0xf, x = x + t)
    DPP_STEP(x, t, 0x143, 0xc, 0xf, x = x + t)
    return x;
}

// Kernel 1: fused match + losses + per-block histogram.
// R14: 512-thread blocks x 32/batch (was 256 x 64). Same 4 priors/thread.
// Halves per-block hists (writeback 12.6 -> 6.3 MB, finishK merge 64 -> 32)
// and block-level fixed costs; denser residency units (3 blocks x 8 waves/CU).
// Ablation ledger: occupancy(R1) x, shuffle->DPP(R2) +9us, fusion(R3) 6x worse,
// fence-join(R4) x, branch-load hoist(R6) x, hist removal(R8) x — distributed
// per-block hist is mandatory (centralized binning serializes, R8).
__global__ void __launch_bounds__(512) mainK(
    const float* __restrict__ loc, const float* __restrict__ conf,
    const float* __restrict__ priors, const float* __restrict__ targets,
    unsigned short* __restrict__ gcnt, float* __restrict__ gsum,
    unsigned long long* __restrict__ bestPart,
    float* __restrict__ part_ll, float* __restrict__ part_pc, int* __restrict__ part_np)
{
    const int bx = blockIdx.x, b = blockIdx.y, tid = threadIdx.x;

    __shared__ float4 trb[NT_];   // x0,y0,x1,y1
    __shared__ float tra[NT_];    // area
    __shared__ int hc[HB];
    __shared__ float hs[HB];
    __shared__ unsigned wkey[8][NT_], wp[8][NT_];
    __shared__ float sh_ll[8], sh_pc[8];
    __shared__ int sh_np[8];

    for (int i = tid; i < HB; i += 512) { hc[i] = 0; hs[i] = 0.0f; }
    if (tid < NT_) {
        const float* tp = targets + ((size_t)b * NT_ + tid) * 5;
        float x0 = tp[0], y0 = tp[1], x1 = tp[2], y1 = tp[3];
        trb[tid] = make_float4(x0, y0, x1, y1);
        tra[tid] = (x1 - x0) * (y1 - y0);
    }
    __syncthreads();

    const int pbase = bx * 2048 + tid;
    float pbx0[4], pby0[4], pbx1[4], pby1[4], par[4];
    float2 cxy[4];
#pragma unroll
    for (int i = 0; i < 4; i++) {
        float4 pr = ((const float4*)priors)[pbase + 512 * i];
        cxy[i] = ((const float2*)conf)[(size_t)b * NP_ + pbase + 512 * i];  // in flight during t-loop
        float hw = pr.z * 0.5f, hh = pr.w * 0.5f;
        pbx0[i] = pr.x - hw; pby0[i] = pr.y - hh;
        pbx1[i] = pr.x + hw; pby1[i] = pr.y + hh;
        par[i] = (pbx1[i] - pbx0[i]) * (pby1[i] - pby0[i]);
    }

    unsigned pkey[4] = {0u, 0u, 0u, 0u};  // per-prior best (iou_key | (15-t))
    unsigned tkey[NT_];                   // per-truth best (iou_key | (15-i))
#pragma unroll
    for (int t = 0; t < NT_; t++) tkey[t] = 0u;

#pragma unroll
    for (int t = 0; t < NT_; t++) {
        float4 tb = trb[t];          // ds_read_b128 (broadcast)
        float ta = tra[t];           // ds_read_b32
#pragma unroll
        for (int i = 0; i < 4; i++) {
            float iou = iou_fast(tb.x, tb.y, tb.z, tb.w, ta,
                                 pbx0[i], pby0[i], pbx1[i], pby1[i], par[i]);
            // monotone u32 key; 2 LSB mantissa bits -> 4-bit tie-break index
            // (ties prefer smaller t / smaller prior index; p monotone in i)
            unsigned base = (__float_as_uint(iou) & 0xFFFFFFFCu) << 2;
            unsigned kt = base | (unsigned)(15 - t);
            unsigned kp = base | (unsigned)(15 - i);
            pkey[i] = (kt > pkey[i]) ? kt : pkey[i];
            tkey[t] = (kp > tkey[t]) ? kp : tkey[t];
        }
    }

    float ll_acc = 0.0f, pc_acc = 0.0f;
    int np_acc = 0;
#pragma unroll
    for (int i = 0; i < 4; i++) {
        int p = pbase + 512 * i;
        size_t bp = (size_t)b * NP_ + p;
        bool pos = (pkey[i] >= 0xFC000000u);  // iou >= 0.5 (0.5 has zero low bits)
        float dd = cxy[i].y - cxy[i].x;
        float v = pos ? 0.0f : softplus_(dd);  // loss_c_mine
        int bin = min(HB - 1, (int)(v * HSCALE));
        atomicAdd(&hc[bin], 1);
        atomicAdd(&hs[bin], v);
        if (pos) {
            np_acc++;
            pc_acc += softplus_(-dd);  // lse - c.y
            int t = 15 - (int)(pkey[i] & 15u);
            float4 tb = trb[t];
            float4 prv = ((const float4*)priors)[p];  // reload: same bits as staging load
            float gcx = ((tb.x + tb.z) * 0.5f - prv.x) / (0.1f * prv.z);
            float gcy = ((tb.y + tb.w) * 0.5f - prv.y) / (0.1f * prv.w);
            float gw = __logf((tb.z - tb.x) / prv.z) * 5.0f;
            float gh = __logf((tb.w - tb.y) / prv.w) * 5.0f;
            float4 ld = ((const float4*)loc)[bp];
            float d0 = fabsf(ld.x - gcx), d1 = fabsf(ld.y - gcy);
            float d2 = fabsf(ld.z - gw),  d3 = fabsf(ld.w - gh);
            ll_acc += (d0 < 1.0f) ? 0.5f * d0 * d0 : d0 - 0.5f;
            ll_acc += (d1 < 1.0f) ? 0.5f * d1 * d1 : d1 - 0.5f;
            ll_acc += (d2 < 1.0f) ? 0.5f * d2 * d2 : d2 - 0.5f;
            ll_acc += (d3 < 1.0f) ? 0.5f * d3 * d3 : d3 - 0.5f;
        }
    }

    // per-wave reductions — DPP chains (VALU), no LDS pipe
    const int wave = tid >> 6, lane = tid & 63;
#pragma unroll
    for (int t = 0; t < NT_; t++) {
        unsigned k = tkey[t];
        unsigned m = (unsigned)__builtin_amdgcn_readlane((int)wave_max_u32(k), 63);
        unsigned long long ball = __ballot(k == m);
        if (lane == 0) {
            int l = __ffsll((long long)ball) - 1;  // lowest lane = smallest p (same i)
            int ci = 15 - (int)(m & 15u);
            int p = bx * 2048 + ci * 512 + wave * 64 + l;
            wkey[wave][t] = m;
            wp[wave][t] = (unsigned)p;
        }
    }
    {
        float llw = wave_sum_f32(ll_acc);
        float pcw = wave_sum_f32(pc_acc);
        int npw = wave_sum_i32(np_acc);
        if (lane == 63) { sh_ll[wave] = llw; sh_pc[wave] = pcw; sh_np[wave] = npw; }
    }
    __syncthreads();

    if (tid < NT_) {
        unsigned bk = wkey[0][tid], bpv = wp[0][tid];
        for (int w = 1; w < 8; w++) {
            unsigned k2 = wkey[w][tid], p2 = wp[w][tid];
            if (k2 > bk || (k2 == bk && p2 < bpv)) { bk = k2; bpv = p2; }
        }
        unsigned long long pk = (((unsigned long long)bk) << 32) | (unsigned)(~bpv);
        bestPart[((size_t)b * NT_ + tid) * NBX + bx] = pk;   // plain store
    }
    if (tid == 0) {
        float a_ll = 0.0f, a_pc = 0.0f; int a_np = 0;
#pragma unroll
        for (int w = 0; w < 8; w++) { a_ll += sh_ll[w]; a_pc += sh_pc[w]; a_np += sh_np[w]; }
        part_ll[b * NBX + bx] = a_ll;
        part_pc[b * NBX + bx] = a_pc;
        part_np[b * NBX + bx] = a_np;
    }
    // deterministic per-block hist writeback (coalesced); counts fit u16 (<=2048)
    unsigned short* gc = gcnt + ((size_t)(b * NBX + bx)) * HB;
    float* gs = gsum + ((size_t)(b * NBX + bx)) * HB;
    for (int i = tid; i < HB; i += 512) { gc[i] = (unsigned short)hc[i]; gs[i] = hs[i]; }
}

// Kernel 2 (R11 structure): one block per batch, FULLY independent — zero
// fences, zero tickets, zero global atomics (R3/R4 lesson). Merges NBX=32
// per-block hists (one bin/thread, j split into two fixed-order halves);
// bestPart via 16 waves x 32-lane shuffle-max (u64 keys unique -> order-free);
// part sums via DPP fixed tree with masked lanes. lastK does the division.
__global__ void __launch_bounds__(1024) finishK(
    const float* __restrict__ loc, const float* __restrict__ conf,
    const float* __restrict__ priors, const float* __restrict__ targets,
    const unsigned short* __restrict__ gcnt, const float* __restrict__ gsum,
    const unsigned long long* __restrict__ bestPart,
    const float* __restrict__ part_ll, const float* __restrict__ part_pc,
    const int* __restrict__ part_np,
    float* __restrict__ final_l, float* __restrict__ final_c, int* __restrict__ final_n)
{
    const int b = blockIdx.x, tid = threadIdx.x;  // 1024 threads
    __shared__ int hc[HB];
    __shared__ float hs[HB];
    __shared__ float4 trb[NT_];
    __shared__ float tra[NT_];
    __shared__ unsigned ps[NT_];
    __shared__ float s_dll, s_dpc, s_sll, s_spc;
    __shared__ int s_dnp, s_sn;
    __shared__ unsigned ccnt[16];
    __shared__ float csm[16];

    if (tid == 0) { s_dll = 0.0f; s_dpc = 0.0f; s_dnp = 0; }
    if (tid < NT_) {
        const float* tp = targets + ((size_t)b * NT_ + tid) * 5;
        float x0 = tp[0], y0 = tp[1], x1 = tp[2], y1 = tp[3];
        trb[tid] = make_float4(x0, y0, x1, y1);
        tra[tid] = (x1 - x0) * (y1 - y0);
    }

    // hist merge: one bin per thread; j-range in two fixed-order halves
    {
        const size_t base = (size_t)(b * NBX) * HB + tid;
        int cA = 0, cB = 0; float sA = 0.0f, sB = 0.0f;
#pragma unroll 8
        for (int j = 0; j < 16; j++) {
            size_t oA = base + (size_t)j * HB;
            size_t oB = base + (size_t)(16 + j) * HB;
            cA += (int)gcnt[oA]; sA += gsum[oA];
            cB += (int)gcnt[oB]; sB += gsum[oB];
        }
        hc[tid] = cA + cB;          // fixed combine order -> deterministic
        hs[tid] = sA + sB;
    }

    // bestPart: one wave per truth, lanes 0..31 = 32 partials; u64 max is
    // order-free and keys are unique (low bits = ~p) -> deterministic.
    // Lanes >=32 contribute 0 (real keys have key>=12 -> 0 never wins).
    {
        const int tr_i = tid >> 6, lane = tid & 63;
        unsigned long long v = (lane < NBX)
            ? bestPart[((size_t)b * NT_ + tr_i) * NBX + lane] : 0ull;
        for (int off = 32; off > 0; off >>= 1) {
            unsigned long long u = __shfl_down(v, off, 64);
            v = (u > v) ? u : v;
        }
        if (lane == 0) ps[tr_i] = ~((unsigned)(v & 0xffffffffULL));
    }
    // part sums: lanes 0..31 live, fixed DPP tree (deterministic; 0-padded)
    if (tid < 64) {
        float lv = (tid < NBX) ? part_ll[b * NBX + tid] : 0.0f;
        float pv = (tid < NBX) ? part_pc[b * NBX + tid] : 0.0f;
        int nv = (tid < NBX) ? part_np[b * NBX + tid] : 0;
        lv = wave_sum_f32(lv); pv = wave_sum_f32(pv); nv = wave_sum_i32(nv);
        if (tid == 63) { s_sll = lv; s_spc = pv; s_sn = nv; }
    }
    __syncthreads();

    // fixup (16 threads) — adjustments into LDS; identical math to main pass
    if (tid < NT_) {
        unsigned p = ps[tid];
        bool active = true;
        for (int u = tid + 1; u < NT_; u++)
            if (ps[u] == p) { active = false; break; }  // last-wins dedup
        if (active) {
            float4 prv = ((const float4*)priors)[p];
            float hw = prv.z * 0.5f, hh = prv.w * 0.5f;
            float qx0 = prv.x - hw, qy0 = prv.y - hh;
            float qx1 = prv.x + hw, qy1 = prv.y + hh;
            float areab = (qx1 - qx0) * (qy1 - qy0);
            unsigned pk = 0u;
            for (int tt = 0; tt < NT_; tt++) {
                float4 tb = trb[tt];
                float iou = iou_fast(tb.x, tb.y, tb.z, tb.w, tra[tt],
                                     qx0, qy0, qx1, qy1, areab);
                unsigned cand = ((__float_as_uint(iou) & 0xFFFFFFFCu) << 2)
                              | (unsigned)(15 - tt);
                pk = (cand > pk) ? cand : pk;
            }
            bool pos0 = (pk >= 0xFC000000u);   // identical rule to kernel1
            int t0 = 15 - (int)(pk & 15u);
            size_t bp = (size_t)b * NP_ + p;
            float2 cxyf = ((const float2*)conf)[bp];
            float dd = cxyf.y - cxyf.x;
            float4 ld = ((const float4*)loc)[bp];

            auto sl1_of = [&](int tt) -> float {
                float4 tb = trb[tt];
                float gcx = ((tb.x + tb.z) * 0.5f - prv.x) / (0.1f * prv.z);
                float gcy = ((tb.y + tb.w) * 0.5f - prv.y) / (0.1f * prv.w);
                float gw = __logf((tb.z - tb.x) / prv.z) * 5.0f;
                float gh = __logf((tb.w - tb.y) / prv.w) * 5.0f;
                float d0 = fabsf(ld.x - gcx), d1 = fabsf(ld.y - gcy);
                float d2 = fabsf(ld.z - gw),  d3 = fabsf(ld.w - gh);
                float s = (d0 < 1.0f) ? 0.5f * d0 * d0 : d0 - 0.5f;
                s += (d1 < 1.0f) ? 0.5f * d1 * d1 : d1 - 0.5f;
                s += (d2 < 1.0f) ? 0.5f * d2 * d2 : d2 - 0.5f;
                s += (d3 < 1.0f) ? 0.5f * d3 * d3 : d3 - 0.5f;
                return s;
            };
            float dll = sl1_of(tid) - (pos0 ? sl1_of(t0) : 0.0f);
            atomicAdd(&s_dll, dll);            // LDS atomic, single wave -> fixed HW order
            if (!pos0) {
                float v = softplus_(dd);       // identical expr to binned value
                int bin = min(HB - 1, (int)(v * HSCALE));
                atomicSub(&hc[bin], 1);
                atomicAdd(&hs[bin], -v);
                atomicAdd(&s_dpc, softplus_(-dd));
                atomicAdd(&s_dnp, 1);
            }
        }
    }
    __syncthreads();

    if (tid < 16) {
        unsigned cacc = 0; float sacc = 0.0f;
        for (int j = 0; j < 64; j++) { cacc += (unsigned)hc[tid * 64 + j]; sacc += hs[tid * 64 + j]; }
        ccnt[tid] = cacc; csm[tid] = sacc;
    }
    __syncthreads();

    if (tid == 0) {
        float sll = s_sll + s_dll;
        float spc = s_spc + s_dpc;
        int n = s_sn + s_dnp;
        int K = 3 * n;
        if (K > NP_ - 1) K = NP_ - 1;
        float tk = 0.0f;
        if (K > 0) {
            unsigned need = (unsigned)K, cum = 0;
            float s = 0.0f;
            int cb = 15;
            for (; cb > 0; --cb) {
                if (cum + ccnt[cb] >= need) break;
                cum += ccnt[cb]; s += csm[cb];
            }
            int bin = cb * 64 + 63;
            for (; bin > cb * 64; --bin) {
                if (cum + (unsigned)hc[bin] >= need) break;
                cum += (unsigned)hc[bin]; s += hs[bin];
            }
            unsigned rem = need - cum;
            int cv = hc[bin];
            float avg = (cv > 0) ? __fdividef(hs[bin], (float)cv) : 0.0f;
            tk = s + (float)rem * avg;
        }
        final_l[b] = sll;
        final_c[b] = spc + tk;
        final_n[b] = n;
        // no fence: kernel boundary orders these stores before lastK
    }
}

// Kernel 3: trivial cross-batch reduce. Ordered by kernel boundary.
__global__ void __launch_bounds__(64) lastK(
    const float* __restrict__ final_l, const float* __restrict__ final_c,
    const int* __restrict__ final_n, float* __restrict__ out)
{
    const int tid = threadIdx.x;
    float lv = 0.0f, cv = 0.0f;
    int nv = 0;
    if (tid < NB_) { lv = final_l[tid]; cv = final_c[tid]; nv = final_n[tid]; }
    for (int off = 32; off > 0; off >>= 1) {
        lv += __shfl_down(lv, off, 64);
        cv += __shfl_down(cv, off, 64);
        nv += __shfl_down(nv, off, 64);
    }
    if (tid == 0) {
        float fn = (float)nv;
        out[0] = lv / fn;
        out[1] = cv / fn;
    }
}

extern "C" void kernel_launch(void* const* d_in, const int* in_sizes, int n_in,
                              void* d_out, int out_size, void* d_ws, size_t ws_size,
                              hipStream_t stream) {
    const float* loc = (const float*)d_in[0];
    const float* conf = (const float*)d_in[1];
    const float* priors = (const float*)d_in[2];
    const float* targets = (const float*)d_in[3];
    float* out = (float*)d_out;

    char* w = (char*)d_ws;
    unsigned short* gcnt = (unsigned short*)w;             // 32*32*1024*2 = 2 MB
    float* gsum = (float*)(w + (2u << 20));                // 32*32*1024*4 = 4 MB
    char* acc = w + (6u << 20);
    unsigned long long* bestPart = (unsigned long long*)acc;        // 32*16*32*8 = 128 KB
    float* part_ll = (float*)(acc + 131072);                        // 4 KB
    float* part_pc = (float*)(acc + 135168);                        // 4 KB
    int* part_np   = (int*)(acc + 139264);                          // 4 KB
    float* final_l = (float*)(acc + 143360);                        // 128 B
    float* final_c = (float*)(acc + 143488);                        // 128 B
    int* final_n   = (int*)(acc + 143616);                          // 128 B

    mainK<<<dim3(NBX, NB_), 512, 0, stream>>>(loc, conf, priors, targets,
                                              gcnt, gsum, bestPart,
                                              part_ll, part_pc, part_np);
    finishK<<<NB_, 1024, 0, stream>>>(loc, conf, priors, targets,
                                      gcnt, gsum, bestPart,
                                      part_ll, part_pc, part_np,
                                      final_l, final_c, final_n);
    lastK<<<1, 64, 0, stream>>>(final_l, final_c, final_n, out);
}

// Round 10
// 137.813 us; speedup vs baseline: 1.5747x; 1.0700x over previous
//
#include <hip/hip_runtime.h>

#define NB_ 32
#define NP_ 65536
#define NT_ 16
#define HB 1024
#define HSCALE 128.0f
#define NBX 16     // kernel1 blocks per batch (4096 priors each, 512 threads, 8/thread)
#define PRT 8      // priors per thread (ILP width)

__device__ __forceinline__ float softplus_(float x) {
    // log(1 + e^x), stable
    return fmaxf(x, 0.0f) + __logf(1.0f + __expf(-fabsf(x)));
}

__device__ __forceinline__ float iou_fast(float tx0, float ty0, float tx1, float ty1, float ta,
                                          float bx0, float by0, float bx1, float by1, float ar) {
    float lx = fmaxf(tx0, bx0), ly = fmaxf(ty0, by0);
    float rx = fminf(tx1, bx1), ry = fminf(ty1, by1);
    float w = fmaxf(rx - lx, 0.0f), h = fmaxf(ry - ly, 0.0f);
    float inter = w * h;
    return __fdividef(inter, ta + ar - inter);
}

// ---- DPP wave64 reductions (result valid in lane 63) ----
#define DPP_STEP(x, t, ctrl, rmask, bmask, OP)                                          \
    t = __builtin_amdgcn_update_dpp(0, (x), (ctrl), (rmask), (bmask), true); OP;

__device__ __forceinline__ unsigned wave_max_u32(unsigned v) {
    int x = (int)v, t;
    DPP_STEP(x, t, 0x111, 0xf, 0xf, x = ((unsigned)t > (unsigned)x) ? t : x)
    DPP_STEP(x, t, 0x112, 0xf, 0xf, x = ((unsigned)t > (unsigned)x) ? t : x)
    DPP_STEP(x, t, 0x114, 0xf, 0xe, x = ((unsigned)t > (unsigned)x) ? t : x)
    DPP_STEP(x, t, 0x118, 0xf, 0xc, x = ((unsigned)t > (unsigned)x) ? t : x)
    DPP_STEP(x, t, 0x142, 0xa, 0xf, x = ((unsigned)t > (unsigned)x) ? t : x)
    DPP_STEP(x, t, 0x143, 0xc, 0xf, x = ((unsigned)t > (unsigned)x) ? t : x)
    return (unsigned)x;
}

__device__ __forceinline__ float wave_sum_f32(float v) {
    int x = __float_as_int(v), t;
    float f;
    DPP_STEP(x, t, 0x111, 0xf, 0xf, f = __int_as_float(x) + __int_as_float(t); x = __float_as_int(f))
    DPP_STEP(x, t, 0x112, 0xf, 0xf, f = __int_as_float(x) + __int_as_float(t); x = __float_as_int(f))
    DPP_STEP(x, t, 0x114, 0xf, 0xe, f = __int_as_float(x) + __int_as_float(t); x = __float_as_int(f))
    DPP_STEP(x, t, 0x118, 0xf, 0xc, f = __int_as_float(x) + __int_as_float(t); x = __float_as_int(f))
    DPP_STEP(x, t, 0x142, 0xa, 0xf, f = __int_as_float(x) + __int_as_float(t); x = __float_as_int(f))
    DPP_STEP(x, t, 0x143, 0xc, 0xf, f = __int_as_float(x) + __int_as_float(t); x = __float_as_int(f))
    return __int_as_float(x);
}

__device__ __forceinline__ int wave_sum_i32(int v) {
    int x = v, t;
    DPP_STEP(x, t, 0x111, 0xf, 0xf, x = x + t)
    DPP_STEP(x, t, 0x112, 0xf, 0xf, x = x + t)
    DPP_STEP(x, t, 0x114, 0xf, 0xe, x = x + t)
    DPP_STEP(x, t, 0x118, 0xf, 0xc, x = x + t)
    DPP_STEP(x, t, 0x142, 0xa, 0xf, x = x + t)
    DPP_STEP(x, t, 0x143, 0xc, 0xf, x = x + t)
    return x;
}

// Kernel 1: fused match + losses + per-block histogram.
// R15: 8 priors/thread INTERLEAVED (8 independent IoU chains per thread) —
// the one untested axis. Prior rounds: occupancy(R1) x, shuffle->DPP(R2) +9us,
// fusion(R3) 6x worse, fence-join(R4) x, branch-load hoist(R6) x, hist
// removal(R8) x (distributed hist mandatory), geometry 256->512(R14) null.
// VALUBusy stuck 52-72% with all waves co-stalled -> betting on dep-chain ILP.
__global__ void __launch_bounds__(512) mainK(
    const float* __restrict__ loc, const float* __restrict__ conf,
    const float* __restrict__ priors, const float* __restrict__ targets,
    unsigned short* __restrict__ gcnt, float* __restrict__ gsum,
    unsigned long long* __restrict__ bestPart,
    float* __restrict__ part_ll, float* __restrict__ part_pc, int* __restrict__ part_np)
{
    const int bx = blockIdx.x, b = blockIdx.y, tid = threadIdx.x;

    __shared__ float4 trb[NT_];   // x0,y0,x1,y1
    __shared__ float tra[NT_];    // area
    __shared__ int hc[HB];
    __shared__ float hs[HB];
    __shared__ unsigned wkey[8][NT_], wp[8][NT_];
    __shared__ float sh_ll[8], sh_pc[8];
    __shared__ int sh_np[8];

    for (int i = tid; i < HB; i += 512) { hc[i] = 0; hs[i] = 0.0f; }
    if (tid < NT_) {
        const float* tp = targets + ((size_t)b * NT_ + tid) * 5;
        float x0 = tp[0], y0 = tp[1], x1 = tp[2], y1 = tp[3];
        trb[tid] = make_float4(x0, y0, x1, y1);
        tra[tid] = (x1 - x0) * (y1 - y0);
    }
    __syncthreads();

    const int pbase = bx * (512 * PRT) + tid;
    float pbx0[PRT], pby0[PRT], pbx1[PRT], pby1[PRT], par[PRT];
    float2 cxy[PRT];
#pragma unroll
    for (int i = 0; i < PRT; i++) {
        float4 pr = ((const float4*)priors)[pbase + 512 * i];
        cxy[i] = ((const float2*)conf)[(size_t)b * NP_ + pbase + 512 * i];  // in flight during t-loop
        float hw = pr.z * 0.5f, hh = pr.w * 0.5f;
        pbx0[i] = pr.x - hw; pby0[i] = pr.y - hh;
        pbx1[i] = pr.x + hw; pby1[i] = pr.y + hh;
        par[i] = (pbx1[i] - pbx0[i]) * (pby1[i] - pby0[i]);
    }

    unsigned pkey[PRT];                   // per-prior best (iou_key | (15-t))
    unsigned tkey[NT_];                   // per-truth best (iou_key | (15-i))
#pragma unroll
    for (int i = 0; i < PRT; i++) pkey[i] = 0u;
#pragma unroll
    for (int t = 0; t < NT_; t++) tkey[t] = 0u;

#pragma unroll
    for (int t = 0; t < NT_; t++) {
        float4 tb = trb[t];          // ds_read_b128 (broadcast)
        float ta = tra[t];           // ds_read_b32
#pragma unroll
        for (int i = 0; i < PRT; i++) {   // 8 independent chains
            float iou = iou_fast(tb.x, tb.y, tb.z, tb.w, ta,
                                 pbx0[i], pby0[i], pbx1[i], pby1[i], par[i]);
            // monotone u32 key; 2 LSB mantissa bits -> 4-bit tie-break index
            // (ties prefer smaller t / smaller prior index; p monotone in i)
            unsigned base = (__float_as_uint(iou) & 0xFFFFFFFCu) << 2;
            unsigned kt = base | (unsigned)(15 - t);
            unsigned kp = base | (unsigned)(15 - i);
            pkey[i] = (kt > pkey[i]) ? kt : pkey[i];
            tkey[t] = (kp > tkey[t]) ? kp : tkey[t];
        }
    }

    float ll_acc = 0.0f, pc_acc = 0.0f;
    int np_acc = 0;
#pragma unroll
    for (int i = 0; i < PRT; i++) {
        int p = pbase + 512 * i;
        size_t bp = (size_t)b * NP_ + p;
        bool pos = (pkey[i] >= 0xFC000000u);  // iou >= 0.5 (0.5 has zero low bits)
        float dd = cxy[i].y - cxy[i].x;
        float v = pos ? 0.0f : softplus_(dd);  // loss_c_mine
        int bin = min(HB - 1, (int)(v * HSCALE));
        atomicAdd(&hc[bin], 1);
        atomicAdd(&hs[bin], v);
        if (pos) {
            np_acc++;
            pc_acc += softplus_(-dd);  // lse - c.y
            int t = 15 - (int)(pkey[i] & 15u);
            float4 tb = trb[t];
            float4 prv = ((const float4*)priors)[p];  // reload: same bits as staging load
            float gcx = ((tb.x + tb.z) * 0.5f - prv.x) / (0.1f * prv.z);
            float gcy = ((tb.y + tb.w) * 0.5f - prv.y) / (0.1f * prv.w);
            float gw = __logf((tb.z - tb.x) / prv.z) * 5.0f;
            float gh = __logf((tb.w - tb.y) / prv.w) * 5.0f;
            float4 ld = ((const float4*)loc)[bp];
            float d0 = fabsf(ld.x - gcx), d1 = fabsf(ld.y - gcy);
            float d2 = fabsf(ld.z - gw),  d3 = fabsf(ld.w - gh);
            ll_acc += (d0 < 1.0f) ? 0.5f * d0 * d0 : d0 - 0.5f;
            ll_acc += (d1 < 1.0f) ? 0.5f * d1 * d1 : d1 - 0.5f;
            ll_acc += (d2 < 1.0f) ? 0.5f * d2 * d2 : d2 - 0.5f;
            ll_acc += (d3 < 1.0f) ? 0.5f * d3 * d3 : d3 - 0.5f;
        }
    }

    // per-wave reductions — DPP chains (VALU), no LDS pipe
    const int wave = tid >> 6, lane = tid & 63;
#pragma unroll
    for (int t = 0; t < NT_; t++) {
        unsigned k = tkey[t];
        unsigned m = (unsigned)__builtin_amdgcn_readlane((int)wave_max_u32(k), 63);
        unsigned long long ball = __ballot(k == m);
        if (lane == 0) {
            int l = __ffsll((long long)ball) - 1;  // lowest lane = smallest p (same i)
            int ci = 15 - (int)(m & 15u);
            int p = bx * (512 * PRT) + ci * 512 + wave * 64 + l;
            wkey[wave][t] = m;
            wp[wave][t] = (unsigned)p;
        }
    }
    {
        float llw = wave_sum_f32(ll_acc);
        float pcw = wave_sum_f32(pc_acc);
        int npw = wave_sum_i32(np_acc);
        if (lane == 63) { sh_ll[wave] = llw; sh_pc[wave] = pcw; sh_np[wave] = npw; }
    }
    __syncthreads();

    if (tid < NT_) {
        unsigned bk = wkey[0][tid], bpv = wp[0][tid];
        for (int w = 1; w < 8; w++) {
            unsigned k2 = wkey[w][tid], p2 = wp[w][tid];
            if (k2 > bk || (k2 == bk && p2 < bpv)) { bk = k2; bpv = p2; }
        }
        unsigned long long pk = (((unsigned long long)bk) << 32) | (unsigned)(~bpv);
        bestPart[((size_t)b * NT_ + tid) * NBX + bx] = pk;   // plain store
    }
    if (tid == 0) {
        float a_ll = 0.0f, a_pc = 0.0f; int a_np = 0;
#pragma unroll
        for (int w = 0; w < 8; w++) { a_ll += sh_ll[w]; a_pc += sh_pc[w]; a_np += sh_np[w]; }
        part_ll[b * NBX + bx] = a_ll;
        part_pc[b * NBX + bx] = a_pc;
        part_np[b * NBX + bx] = a_np;
    }
    // deterministic per-block hist writeback (coalesced); counts fit u16 (<=4096)
    unsigned short* gc = gcnt + ((size_t)(b * NBX + bx)) * HB;
    float* gs = gsum + ((size_t)(b * NBX + bx)) * HB;
    for (int i = tid; i < HB; i += 512) { gc[i] = (unsigned short)hc[i]; gs[i] = hs[i]; }
}

// Kernel 2: one block per batch, FULLY independent — zero fences, zero
// tickets, zero global atomics (R3/R4 lesson). Merges NBX=16 per-block hists
// (one bin/thread, j split into two fixed-order halves); bestPart via 16
// waves with lanes 0..15 live (u64 keys unique -> order-free); part sums via
// DPP fixed tree with 0-padded lanes. lastK does the division.
__global__ void __launch_bounds__(1024) finishK(
    const float* __restrict__ loc, const float* __restrict__ conf,
    const float* __restrict__ priors, const float* __restrict__ targets,
    const unsigned short* __restrict__ gcnt, const float* __restrict__ gsum,
    const unsigned long long* __restrict__ bestPart,
    const float* __restrict__ part_ll, const float* __restrict__ part_pc,
    const int* __restrict__ part_np,
    float* __restrict__ final_l, float* __restrict__ final_c, int* __restrict__ final_n)
{
    const int b = blockIdx.x, tid = threadIdx.x;  // 1024 threads
    __shared__ int hc[HB];
    __shared__ float hs[HB];
    __shared__ float4 trb[NT_];
    __shared__ float tra[NT_];
    __shared__ unsigned ps[NT_];
    __shared__ float s_dll, s_dpc, s_sll, s_spc;
    __shared__ int s_dnp, s_sn;
    __shared__ unsigned ccnt[16];
    __shared__ float csm[16];

    if (tid == 0) { s_dll = 0.0f; s_dpc = 0.0f; s_dnp = 0; }
    if (tid < NT_) {
        const float* tp = targets + ((size_t)b * NT_ + tid) * 5;
        float x0 = tp[0], y0 = tp[1], x1 = tp[2], y1 = tp[3];
        trb[tid] = make_float4(x0, y0, x1, y1);
        tra[tid] = (x1 - x0) * (y1 - y0);
    }

    // hist merge: one bin per thread; j-range in two fixed-order halves
    {
        const size_t base = (size_t)(b * NBX) * HB + tid;
        int cA = 0, cB = 0; float sA = 0.0f, sB = 0.0f;
#pragma unroll
        for (int j = 0; j < 8; j++) {
            size_t oA = base + (size_t)j * HB;
            size_t oB = base + (size_t)(8 + j) * HB;
            cA += (int)gcnt[oA]; sA += gsum[oA];
            cB += (int)gcnt[oB]; sB += gsum[oB];
        }
        hc[tid] = cA + cB;          // fixed combine order -> deterministic
        hs[tid] = sA + sB;
    }

    // bestPart: one wave per truth, lanes 0..15 = 16 partials; u64 max is
    // order-free and keys are unique (low bits = ~p) -> deterministic.
    // Lanes >=16 contribute 0 (real keys have key>=8 -> 0 never wins).
    {
        const int tr_i = tid >> 6, lane = tid & 63;
        unsigned long long v = (lane < NBX)
            ? bestPart[((size_t)b * NT_ + tr_i) * NBX + lane] : 0ull;
        for (int off = 32; off > 0; off >>= 1) {
            unsigned long long u = __shfl_down(v, off, 64);
            v = (u > v) ? u : v;
        }
        if (lane == 0) ps[tr_i] = ~((unsigned)(v & 0xffffffffULL));
    }
    // part sums: lanes 0..15 live, fixed DPP tree (deterministic; 0-padded)
    if (tid < 64) {
        float lv = (tid < NBX) ? part_ll[b * NBX + tid] : 0.0f;
        float pv = (tid < NBX) ? part_pc[b * NBX + tid] : 0.0f;
        int nv = (tid < NBX) ? part_np[b * NBX + tid] : 0;
        lv = wave_sum_f32(lv); pv = wave_sum_f32(pv); nv = wave_sum_i32(nv);
        if (tid == 63) { s_sll = lv; s_spc = pv; s_sn = nv; }
    }
    __syncthreads();

    // fixup (16 threads) — adjustments into LDS; identical math to main pass
    if (tid < NT_) {
        unsigned p = ps[tid];
        bool active = true;
        for (int u = tid + 1; u < NT_; u++)
            if (ps[u] == p) { active = false; break; }  // last-wins dedup
        if (active) {
            float4 prv = ((const float4*)priors)[p];
            float hw = prv.z * 0.5f, hh = prv.w * 0.5f;
            float qx0 = prv.x - hw, qy0 = prv.y - hh;
            float qx1 = prv.x + hw, qy1 = prv.y + hh;
            float areab = (qx1 - qx0) * (qy1 - qy0);
            unsigned pk = 0u;
            for (int tt = 0; tt < NT_; tt++) {
                float4 tb = trb[tt];
                float iou = iou_fast(tb.x, tb.y, tb.z, tb.w, tra[tt],
                                     qx0, qy0, qx1, qy1, areab);
                unsigned cand = ((__float_as_uint(iou) & 0xFFFFFFFCu) << 2)
                              | (unsigned)(15 - tt);
                pk = (cand > pk) ? cand : pk;
            }
            bool pos0 = (pk >= 0xFC000000u);   // identical rule to kernel1
            int t0 = 15 - (int)(pk & 15u);
            size_t bp = (size_t)b * NP_ + p;
            float2 cxyf = ((const float2*)conf)[bp];
            float dd = cxyf.y - cxyf.x;
            float4 ld = ((const float4*)loc)[bp];

            auto sl1_of = [&](int tt) -> float {
                float4 tb = trb[tt];
                float gcx = ((tb.x + tb.z) * 0.5f - prv.x) / (0.1f * prv.z);
                float gcy = ((tb.y + tb.w) * 0.5f - prv.y) / (0.1f * prv.w);
                float gw = __logf((tb.z - tb.x) / prv.z) * 5.0f;
                float gh = __logf((tb.w - tb.y) / prv.w) * 5.0f;
                float d0 = fabsf(ld.x - gcx), d1 = fabsf(ld.y - gcy);
                float d2 = fabsf(ld.z - gw),  d3 = fabsf(ld.w - gh);
                float s = (d0 < 1.0f) ? 0.5f * d0 * d0 : d0 - 0.5f;
                s += (d1 < 1.0f) ? 0.5f * d1 * d1 : d1 - 0.5f;
                s += (d2 < 1.0f) ? 0.5f * d2 * d2 : d2 - 0.5f;
                s += (d3 < 1.0f) ? 0.5f * d3 * d3 : d3 - 0.5f;
                return s;
            };
            float dll = sl1_of(tid) - (pos0 ? sl1_of(t0) : 0.0f);
            atomicAdd(&s_dll, dll);            // LDS atomic, single wave -> fixed HW order
            if (!pos0) {
                float v = softplus_(dd);       // identical expr to binned value
                int bin = min(HB - 1, (int)(v * HSCALE));
                atomicSub(&hc[bin], 1);
                atomicAdd(&hs[bin], -v);
                atomicAdd(&s_dpc, softplus_(-dd));
                atomicAdd(&s_dnp, 1);
            }
        }
    }
    __syncthreads();

    if (tid < 16) {
        unsigned cacc = 0; float sacc = 0.0f;
        for (int j = 0; j < 64; j++) { cacc += (unsigned)hc[tid * 64 + j]; sacc += hs[tid * 64 + j]; }
        ccnt[tid] = cacc; csm[tid] = sacc;
    }
    __syncthreads();

    if (tid == 0) {
        float sll = s_sll + s_dll;
        float spc = s_spc + s_dpc;
        int n = s_sn + s_dnp;
        int K = 3 * n;
        if (K > NP_ - 1) K = NP_ - 1;
        float tk = 0.0f;
        if (K > 0) {
            unsigned need = (unsigned)K, cum = 0;
            float s = 0.0f;
            int cb = 15;
            for (; cb > 0; --cb) {
                if (cum + ccnt[cb] >= need) break;
                cum += ccnt[cb]; s += csm[cb];
            }
            int bin = cb * 64 + 63;
            for (; bin > cb * 64; --bin) {
                if (cum + (unsigned)hc[bin] >= need) break;
                cum += (unsigned)hc[bin]; s += hs[bin];
            }
            unsigned rem = need - cum;
            int cv = hc[bin];
            float avg = (cv > 0) ? __fdividef(hs[bin], (float)cv) : 0.0f;
            tk = s + (float)rem * avg;
        }
        final_l[b] = sll;
        final_c[b] = spc + tk;
        final_n[b] = n;
        // no fence: kernel boundary orders these stores before lastK
    }
}

// Kernel 3: trivial cross-batch reduce. Ordered by kernel boundary.
__global__ void __launch_bounds__(64) lastK(
    const float* __restrict__ final_l, const float* __restrict__ final_c,
    const int* __restrict__ final_n, float* __restrict__ out)
{
    const int tid = threadIdx.x;
    float lv = 0.0f, cv = 0.0f;
    int nv = 0;
    if (tid < NB_) { lv = final_l[tid]; cv = final_c[tid]; nv = final_n[tid]; }
    for (int off = 32; off > 0; off >>= 1) {
        lv += __shfl_down(lv, off, 64);
        cv += __shfl_down(cv, off, 64);
        nv += __shfl_down(nv, off, 64);
    }
    if (tid == 0) {
        float fn = (float)nv;
        out[0] = lv / fn;
        out[1] = cv / fn;
    }
}

extern "C" void kernel_launch(void* const* d_in, const int* in_sizes, int n_in,
                              void* d_out, int out_size, void* d_ws, size_t ws_size,
                              hipStream_t stream) {
    const float* loc = (const float*)d_in[0];
    const float* conf = (const float*)d_in[1];
    const float* priors = (const float*)d_in[2];
    const float* targets = (const float*)d_in[3];
    float* out = (float*)d_out;

    char* w = (char*)d_ws;
    unsigned short* gcnt = (unsigned short*)w;             // 32*16*1024*2 = 1 MB
    float* gsum = (float*)(w + (1u << 20));                // 32*16*1024*4 = 2 MB
    char* acc = w + (3u << 20);
    unsigned long long* bestPart = (unsigned long long*)acc;        // 32*16*16*8 = 64 KB
    float* part_ll = (float*)(acc + 65536);                         // 2 KB
    float* part_pc = (float*)(acc + 67584);                         // 2 KB
    int* part_np   = (int*)(acc + 69632);                           // 2 KB
    float* final_l = (float*)(acc + 71680);                         // 128 B
    float* final_c = (float*)(acc + 71808);                         // 128 B
    int* final_n   = (int*)(acc + 71936);                           // 128 B

    mainK<<<dim3(NBX, NB_), 512, 0, stream>>>(loc, conf, priors, targets,
                                              gcnt, gsum, bestPart,
                                              part_ll, part_pc, part_np);
    finishK<<<NB_, 1024, 0, stream>>>(loc, conf, priors, targets,
                                      gcnt, gsum, bestPart,
                                      part_ll, part_pc, part_np,
                                      final_l, final_c, final_n);
    lastK<<<1, 64, 0, stream>>>(final_l, final_c, final_n, out);
}